// Round 5
// baseline (130.418 us; speedup 1.0000x reference)
//
#include <hip/hip_runtime.h>
#include <math.h>

#define NB 2
#define NO 512
#define NQ 512
#define OUT_DIM 128
#define LPAD 516   // logits row pitch (floats): 16B-mult, bank-staggered

typedef __attribute__((ext_vector_type(8))) _Float16 half8;  // 4 VGPR
typedef __attribute__((ext_vector_type(4))) _Float16 half4;  // 2 VGPR
typedef __attribute__((ext_vector_type(4))) float f32x4;     // MFMA acc

__device__ __forceinline__ float softplus_f(float x) {
  return x > 0.0f ? x + log1pf(expf(-x)) : log1pf(expf(x));
}
__device__ __forceinline__ half8 splat8(_Float16 v) {
  return (half8){v, v, v, v, v, v, v, v};
}
__device__ __forceinline__ half8 fma8(half8 a, half8 b, half8 c) {
  return __builtin_elementwise_fma(a, b, c);
}
__device__ __forceinline__ half8 max8(half8 a, half8 b) {
  return __builtin_elementwise_max(a, b);
}

// ---------------------------------------------------------------------------
// Prep: fused 2-layer MLP -> VT (f16, head-transposed [b][h][d][o]).
__global__ __launch_bounds__(1024) void prep_kernel(
    const float* __restrict__ h_obs, const float* __restrict__ fw1,
    const float* __restrict__ fb1, const float* __restrict__ fw2,
    const float* __restrict__ fb2, _Float16* __restrict__ VT)
{
  __shared__ float s_red[4][4][256];
  __shared__ float s_hid[4][256];
  const int n  = threadIdx.x & 255;
  const int ks = threadIdx.x >> 8;
  const int r0 = blockIdx.x * 4;
  const int k0 = ks * 64;
  float a0 = 0.f, a1 = 0.f, a2 = 0.f, a3 = 0.f;
  #pragma unroll 8
  for (int kk = 0; kk < 64; ++kk) {
    int k = k0 + kk;
    float w = fw1[k * 256 + n];
    a0 = fmaf(h_obs[(r0 + 0) * 256 + k], w, a0);
    a1 = fmaf(h_obs[(r0 + 1) * 256 + k], w, a1);
    a2 = fmaf(h_obs[(r0 + 2) * 256 + k], w, a2);
    a3 = fmaf(h_obs[(r0 + 3) * 256 + k], w, a3);
  }
  s_red[ks][0][n] = a0; s_red[ks][1][n] = a1;
  s_red[ks][2][n] = a2; s_red[ks][3][n] = a3;
  __syncthreads();
  if (ks == 0) {
    float bb = fb1[n];
    #pragma unroll
    for (int r = 0; r < 4; ++r) {
      float v = s_red[0][r][n] + s_red[1][r][n] + s_red[2][r][n] + s_red[3][r][n] + bb;
      s_hid[r][n] = fmaxf(v, 0.f);
    }
  }
  __syncthreads();
  float c0 = 0.f, c1 = 0.f, c2 = 0.f, c3 = 0.f;
  #pragma unroll 8
  for (int kk = 0; kk < 64; ++kk) {
    int k = k0 + kk;
    float w = fw2[k * 256 + n];
    c0 = fmaf(s_hid[0][k], w, c0);
    c1 = fmaf(s_hid[1][k], w, c1);
    c2 = fmaf(s_hid[2][k], w, c2);
    c3 = fmaf(s_hid[3][k], w, c3);
  }
  __syncthreads();
  s_red[ks][0][n] = c0; s_red[ks][1][n] = c1;
  s_red[ks][2][n] = c2; s_red[ks][3][n] = c3;
  __syncthreads();
  if (ks == 0) {
    float bb = fb2[n];
    float vr[4];
    #pragma unroll
    for (int r = 0; r < 4; ++r)
      vr[r] = s_red[0][r][n] + s_red[1][r][n] + s_red[2][r][n] + s_red[3][r][n] + bb;
    // transpose store: thread n owns column (h,d); 4 consecutive o
    const int h  = n >> 5, d = n & 31;
    const int bb_ = r0 >> 9, o0 = r0 & 511;
    half4 pv;
    #pragma unroll
    for (int r = 0; r < 4; ++r) pv[r] = (_Float16)vr[r];
    *(half4*)(VT + ((size_t)((bb_ * 8 + h) * 32 + d)) * 512 + o0) = pv;
  }
}

// ---------------------------------------------------------------------------
// Fused attention + out_proj. QT=2 per block, 512 threads (8 waves).
// Phase 1: f16 MFMA delta; ao built in-register (rank-3 pos projection).
// Phase 2+3: per-wave (=head), barrier-free. Softmax WITHOUT max-sub
//   (logits bounded; exp with +10 shift stays in f16-normal range; shift
//   cancels in normalization; sum butterfly deferred past PV). PV reads VT
//   DIRECTLY to registers with explicit depth-4 named-reg prefetch; first 8
//   loads issued before softmax so cold latency hides under the exp work.
__global__ __launch_bounds__(512, 4) void attn_fused(
    const _Float16* __restrict__ VT,     // [b][h][d][o] f16
    const float* __restrict__ kw1,       // (9, 256)
    const float* __restrict__ kb1,       // (256)
    const float* __restrict__ kw2,       // (256, 8)
    const float* __restrict__ kb2,       // (8)
    const float* __restrict__ log_sigma, // (8)
    const float* __restrict__ pos_obs,   // (B*NO, 3)
    const float* __restrict__ pos_query, // (B*NQ, 3)
    const float* __restrict__ ow, const float* __restrict__ obias,
    const float* __restrict__ vw, const float* __restrict__ vbias,
    float* __restrict__ out)
{
  __shared__ __align__(16) float s_logits[2][8 * LPAD];   // 33024 B
  __shared__ __align__(16) _Float16 s_P16[2][8][520];     // 16640 B (P, f16)
  __shared__ half8 s_Bh[512];                             // 8192 B (kw2 f16 frags)
  __shared__ __align__(16) float s_pool[2048];            // 8192 B
  __shared__ __align__(16) float s_po[3][516];            // 6192 B (pos_obs, SoA)
  __shared__ __align__(16) _Float16 s_co[3][264];         // 1584 B (ao coeff table)
  __shared__ float s_sig[2][8];                           // inv-sigma2, kb2

  _Float16* s_aq2 = (_Float16*)s_pool;   // [2][256] f16 (phase 1 only)
  float*    s_hv   = s_pool;             // [(q*2+kind)*256+hd] (phase 3/4)
  float*    s_pred = s_pool + 1024;      // [ks][mode][q][128]  (phase 4)

  const int t   = threadIdx.x;
  const int bq0 = blockIdx.x * 2;
  const int b   = bq0 >> 9;

  // ---- prologue -----------------------------------------------------------
  float pqx[2], pqy[2], pqz[2];
  #pragma unroll
  for (int q = 0; q < 2; ++q) {
    pqx[q] = pos_query[(bq0 + q) * 3 + 0];
    pqy[q] = pos_query[(bq0 + q) * 3 + 1];
    pqz[q] = pos_query[(bq0 + q) * 3 + 2];
  }
  // aq[q][j] in f16
  {
    const int q = t >> 8, j = t & 255;
    float c0 = kw1[0 * 256 + j] + kw1[6 * 256 + j];
    float c1 = kw1[1 * 256 + j] + kw1[7 * 256 + j];
    float c2 = kw1[2 * 256 + j] + kw1[8 * 256 + j];
    s_aq2[q * 256 + j] = (_Float16)
        fmaf(pqx[q], c0, fmaf(pqy[q], c1, fmaf(pqz[q], c2, kb1[j])));
  }
  // ao coefficient table (rank-3): co[c][j], f16
  if (t < 256) {
    const int j = t;
    s_co[0][j] = (_Float16)(kw1[3 * 256 + j] - kw1[6 * 256 + j]);
    s_co[1][j] = (_Float16)(kw1[4 * 256 + j] - kw1[7 * 256 + j]);
    s_co[2][j] = (_Float16)(kw1[5 * 256 + j] - kw1[8 * 256 + j]);
  }
  // sigma table (once per block, not per thread)
  if (t < 8) {
    s_sig[0][t] = 1.0f / (__expf(2.0f * log_sigma[t]) + 1e-6f);
    s_sig[1][t] = kb2[t];
  }
  // pos_obs SoA; d2 kept in registers for the post-barrier prefill
  float d2q0, d2q1;
  {
    const int o = t;
    const float* p = pos_obs + (size_t)(b * NO + o) * 3;
    float px = p[0], py = p[1], pz = p[2];
    s_po[0][o] = px; s_po[1][o] = py; s_po[2][o] = pz;
    float r0 = pqx[0] - px, r1 = pqy[0] - py, r2 = pqz[0] - pz;
    d2q0 = r0 * r0 + r1 * r1 + r2 * r2;
    r0 = pqx[1] - px; r1 = pqy[1] - py; r2 = pqz[1] - pz;
    d2q1 = r0 * r0 + r1 * r1 + r2 * r2;
  }
  // B fragments: kw2 as f16
  {
    const int kstep = t >> 6, lane = t & 63;
    const int nh = lane & 15;
    const int kb_ = kstep * 32 + ((lane >> 4) & 3) * 8;
    half8 b8;
    #pragma unroll
    for (int i = 0; i < 8; ++i) {
      float v = (nh < 8) ? kw2[(kb_ + i) * 8 + nh] : 0.f;
      b8[i] = (_Float16)v;
    }
    s_Bh[kstep * 64 + lane] = b8;
  }
  __syncthreads();

  // logits prefill (rbf + kb2), o = t, reading the shared sigma table.
  // log(exp(x)+1e-8) ~= max(x, log(1e-8)); clamp region weight < e^-15. 
  {
    const int o = t;
    #pragma unroll
    for (int h = 0; h < 8; ++h) {
      float inv = s_sig[0][h], kbv = s_sig[1][h];
      s_logits[0][h * LPAD + o] = fmaxf(-d2q0 * inv, -18.420681f) + kbv;
      s_logits[1][h * LPAD + o] = fmaxf(-d2q1 * inv, -18.420681f) + kbv;
    }
  }

  // ---- phase 1: f16 MFMA delta; A = relu(aq + pos.co) all in packed f16 ---
  {
    const int wave = t >> 6, lane = t & 63;
    const int quad = lane >> 4, mrow = lane & 15;
    const int tb   = wave * 4;
    _Float16 pxh[4], pyh[4], pzh[4];
    #pragma unroll
    for (int jt = 0; jt < 4; ++jt) {
      const int o = (tb + jt) * 16 + mrow;
      pxh[jt] = (_Float16)s_po[0][o];
      pyh[jt] = (_Float16)s_po[1][o];
      pzh[jt] = (_Float16)s_po[2][o];
    }
    f32x4 C[2][4];
    #pragma unroll
    for (int q = 0; q < 2; ++q)
      #pragma unroll
      for (int jt = 0; jt < 4; ++jt) C[q][jt] = (f32x4){0.f, 0.f, 0.f, 0.f};

    const half8 z8 = {0, 0, 0, 0, 0, 0, 0, 0};
    #pragma unroll
    for (int kstep = 0; kstep < 8; ++kstep) {
      const int koff = kstep * 32 + quad * 8;
      half8 c0 = *(const half8*)&s_co[0][koff];
      half8 c1 = *(const half8*)&s_co[1][koff];
      half8 c2 = *(const half8*)&s_co[2][koff];
      half8 aq0 = *(const half8*)(s_aq2 + koff);
      half8 aq1 = *(const half8*)(s_aq2 + 256 + koff);
      half8 bh  = s_Bh[kstep * 64 + lane];
      #pragma unroll
      for (int jt = 0; jt < 4; ++jt) {
        half8 ao = fma8(splat8(pxh[jt]), c0,
                   fma8(splat8(pyh[jt]), c1, splat8(pzh[jt]) * c2));
        half8 a0 = max8(aq0 + ao, z8);
        half8 a1 = max8(aq1 + ao, z8);
        C[0][jt] = __builtin_amdgcn_mfma_f32_16x16x32_f16(a0, bh, C[0][jt], 0, 0, 0);
        C[1][jt] = __builtin_amdgcn_mfma_f32_16x16x32_f16(a1, bh, C[1][jt], 0, 0, 0);
      }
    }
    __syncthreads();   // prefill complete everywhere before RMW epilogue
    // epilogue: D[n=h=lane&15][m=quad*4+r]; add delta into prefilled logits
    const int hh = lane & 15;
    if (hh < 8) {
      #pragma unroll
      for (int q = 0; q < 2; ++q)
        #pragma unroll
        for (int jt = 0; jt < 4; ++jt) {
          const int ob2 = (tb + jt) * 16 + quad * 4;
          #pragma unroll
          for (int r = 0; r < 4; ++r)
            s_logits[q][hh * LPAD + ob2 + r] += C[q][jt][r];
        }
    }
  }
  __syncthreads();   // logits complete; waves drift from here to phase 4

  // ---- phase 2+3: per-wave (=head), barrier-free --------------------------
  {
    const int h = t >> 6, lane = t & 63;
    const int kg = lane >> 4, dl = lane & 15;
    const _Float16* vt = VT + ((size_t)(b * 8 + h) << 14) + dl * 512;

    // depth-4 register prefetch of VT (am = V[d], am+8192 halves = V[d+16])
    half8 A0a, A0b, A1a, A1b, A2a, A2b, A3a, A3b;
#define LDP(Aa, Ab, s)  do {                                        \
      Aa = *(const half8*)(vt + (s) * 32 + kg * 8);                 \
      Ab = *(const half8*)(vt + 8192 + (s) * 32 + kg * 8); } while (0)
    LDP(A0a, A0b, 0); LDP(A1a, A1b, 1); LDP(A2a, A2b, 2); LDP(A3a, A3b, 3);

    // softmax without max-subtraction: p = exp(min(l+10, 11)); shift cancels
    // in normalization; keeps p in f16-normal range even for all-far rows.
    float s0 = 0.f, s1 = 0.f;
    {
      const float* pl0 = &s_logits[0][h * LPAD];
      const float* pl1 = &s_logits[1][h * LPAD];
      _Float16* pp0 = &s_P16[0][h][0];
      _Float16* pp1 = &s_P16[1][h][0];
      #pragma unroll
      for (int k = 0; k < 8; ++k) {
        float l0 = pl0[k * 64 + lane];
        float l1 = pl1[k * 64 + lane];
        float p0 = __expf(fminf(l0 + 10.f, 11.f));
        float p1 = __expf(fminf(l1 + 10.f, 11.f));
        s0 += p0; s1 += p1;
        pp0[k * 64 + lane] = (_Float16)p0;
        pp1[k * 64 + lane] = (_Float16)p1;
      }
    }

    const _Float16* pB = &s_P16[lane & 1][h][0];
    f32x4 Cm0 = {0.f, 0.f, 0.f, 0.f}, Cm1 = Cm0, Cv0 = Cm0, Cv1 = Cm0;
#define STEP(Aa, Ab, s)  do {                                       \
      half8 pb = *(const half8*)(pB + (s) * 32 + kg * 8);           \
      half8 sqa = Aa * Aa, sqb = Ab * Ab;                           \
      __builtin_amdgcn_s_setprio(1);                                \
      Cm0 = __builtin_amdgcn_mfma_f32_16x16x32_f16(Aa,  pb, Cm0, 0, 0, 0); \
      Cm1 = __builtin_amdgcn_mfma_f32_16x16x32_f16(Ab,  pb, Cm1, 0, 0, 0); \
      Cv0 = __builtin_amdgcn_mfma_f32_16x16x32_f16(sqa, pb, Cv0, 0, 0, 0); \
      Cv1 = __builtin_amdgcn_mfma_f32_16x16x32_f16(sqb, pb, Cv1, 0, 0, 0); \
      __builtin_amdgcn_s_setprio(0); } while (0)

    #pragma unroll
    for (int g = 0; g < 4; ++g) {
      STEP(A0a, A0b, 4 * g + 0); if (g < 3) LDP(A0a, A0b, 4 * g + 4);
      STEP(A1a, A1b, 4 * g + 1); if (g < 3) LDP(A1a, A1b, 4 * g + 5);
      STEP(A2a, A2b, 4 * g + 2); if (g < 3) LDP(A2a, A2b, 4 * g + 6);
      STEP(A3a, A3b, 4 * g + 3); if (g < 3) LDP(A3a, A3b, 4 * g + 7);
    }
#undef STEP
#undef LDP

    // deferred sum reduction (off the PV critical path)
    #pragma unroll
    for (int off = 32; off >= 1; off >>= 1) {
      s0 += __shfl_xor(s0, off, 64);
      s1 += __shfl_xor(s1, off, 64);
    }
    // epilogue: C row = kg*4+r (=d_local), col = nq (=q). Normalize + var.
    const int nq = lane & 15;
    if (nq < 2) {
      const float iv = 1.0f / (nq ? s1 : s0);
      const int dbase = h * 32 + kg * 4;
      f32x4 m0, v0, m1, v1;
      #pragma unroll
      for (int r = 0; r < 4; ++r) {
        float a = Cm0[r] * iv;
        m0[r] = a; v0[r] = fmaxf(Cv0[r] * iv - a * a, 0.f);
        float c = Cm1[r] * iv;
        m1[r] = c; v1[r] = fmaxf(Cv1[r] * iv - c * c, 0.f);
      }
      *(f32x4*)(s_hv + (nq * 2 + 0) * 256 + dbase)      = m0;
      *(f32x4*)(s_hv + (nq * 2 + 1) * 256 + dbase)      = v0;
      *(f32x4*)(s_hv + (nq * 2 + 0) * 256 + dbase + 16) = m1;
      *(f32x4*)(s_hv + (nq * 2 + 1) * 256 + dbase + 16) = v1;
    }
  }
  __syncthreads();

  // ---- phase 4: out_proj, k-split 2, W read once per (mode,ks) ------------
  {
    const int ks = t >> 8, mode = (t >> 7) & 1, n = t & 127;
    const float* W  = mode ? vw : ow;
    const float* X0 = s_hv + mode * 256;        // q0
    const float* X1 = s_hv + (2 + mode) * 256;  // q1
    float a0 = 0.f, a1 = 0.f;
    const int k0 = ks * 128;
    #pragma unroll 4
    for (int k = k0; k < k0 + 128; k += 4) {
      float4 x0 = *(const float4*)&X0[k];
      float4 x1 = *(const float4*)&X1[k];
      float w0 = W[(k + 0) * 128 + n];
      float w1 = W[(k + 1) * 128 + n];
      float w2 = W[(k + 2) * 128 + n];
      float w3 = W[(k + 3) * 128 + n];
      a0 = fmaf(x0.x, w0, a0); a1 = fmaf(x1.x, w0, a1);
      a0 = fmaf(x0.y, w1, a0); a1 = fmaf(x1.y, w1, a1);
      a0 = fmaf(x0.z, w2, a0); a1 = fmaf(x1.z, w2, a1);
      a0 = fmaf(x0.w, w3, a0); a1 = fmaf(x1.w, w3, a1);
    }
    s_pred[((ks * 2 + mode) * 2 + 0) * 128 + n] = a0;   // disjoint from s_hv
    s_pred[((ks * 2 + mode) * 2 + 1) * 128 + n] = a1;
  }
  __syncthreads();
  {
    const int q = t >> 8, mode = (t >> 7) & 1, n = t & 127;
    float v = s_pred[((0 * 2 + mode) * 2 + q) * 128 + n]
            + s_pred[((1 * 2 + mode) * 2 + q) * 128 + n]
            + (mode ? vbias[n] : obias[n]);
    if (mode) v = softplus_f(v);
    out[(size_t)mode * (NB * NQ * OUT_DIM) + (size_t)(bq0 + q) * OUT_DIM + n] = v;
  }
}

// ---------------------------------------------------------------------------
extern "C" void kernel_launch(void* const* d_in, const int* in_sizes, int n_in,
                              void* d_out, int out_size, void* d_ws, size_t ws_size,
                              hipStream_t stream)
{
  const float* h_obs     = (const float*)d_in[0];
  const float* pos_obs   = (const float*)d_in[1];
  const float* pos_query = (const float*)d_in[2];
  const float* fw1       = (const float*)d_in[3];
  const float* fb1       = (const float*)d_in[4];
  const float* fw2       = (const float*)d_in[5];
  const float* fb2       = (const float*)d_in[6];
  const float* log_sigma = (const float*)d_in[7];
  const float* kw1       = (const float*)d_in[8];
  const float* kb1       = (const float*)d_in[9];
  const float* kw2       = (const float*)d_in[10];
  const float* kb2       = (const float*)d_in[11];
  const float* ow        = (const float*)d_in[12];
  const float* ob        = (const float*)d_in[13];
  const float* vw        = (const float*)d_in[14];
  const float* vb        = (const float*)d_in[15];

  float* out = (float*)d_out;
  _Float16* VT = (_Float16*)d_ws;   // 262144 f16 = 512 KB

  prep_kernel<<<256, 1024, 0, stream>>>(h_obs, fw1, fb1, fw2, fb2, VT);
  attn_fused<<<NB * NQ / 2, 512, 0, stream>>>(VT, kw1, kb1, kw2, kb2,
                                              log_sigma, pos_obs, pos_query,
                                              ow, ob, vw, vb, out);
}

// Round 6
// 125.433 us; speedup vs baseline: 1.0397x; 1.0397x over previous
//
#include <hip/hip_runtime.h>
#include <math.h>

#define NB 2
#define NO 512
#define NQ 512
#define OUT_DIM 128
#define LPAD 516   // logits row pitch (floats): 16B-mult, bank-staggered

typedef __attribute__((ext_vector_type(8))) _Float16 half8;  // 4 VGPR
typedef __attribute__((ext_vector_type(4))) _Float16 half4;  // 2 VGPR
typedef __attribute__((ext_vector_type(4))) float f32x4;     // MFMA acc

__device__ __forceinline__ float softplus_f(float x) {
  return x > 0.0f ? x + log1pf(expf(-x)) : log1pf(expf(x));
}
__device__ __forceinline__ half8 splat8(_Float16 v) {
  return (half8){v, v, v, v, v, v, v, v};
}
__device__ __forceinline__ half8 fma8(half8 a, half8 b, half8 c) {
  return __builtin_elementwise_fma(a, b, c);
}
__device__ __forceinline__ half8 max8(half8 a, half8 b) {
  return __builtin_elementwise_max(a, b);
}
// async global->LDS, 16B per lane; dest = lds_base + lane*16 (wave-uniform base)
__device__ __forceinline__ void gll16(const void* g, void* l) {
  __builtin_amdgcn_global_load_lds(
      (const __attribute__((address_space(1))) unsigned int*)g,
      (__attribute__((address_space(3))) unsigned int*)l, 16, 0, 0);
}

// ---------------------------------------------------------------------------
// Prep: fused 2-layer MLP -> VT (f16, head-transposed [b][h][d][o]).
__global__ __launch_bounds__(1024) void prep_kernel(
    const float* __restrict__ h_obs, const float* __restrict__ fw1,
    const float* __restrict__ fb1, const float* __restrict__ fw2,
    const float* __restrict__ fb2, _Float16* __restrict__ VT)
{
  __shared__ float s_red[4][4][256];
  __shared__ float s_hid[4][256];
  const int n  = threadIdx.x & 255;
  const int ks = threadIdx.x >> 8;
  const int r0 = blockIdx.x * 4;
  const int k0 = ks * 64;
  float a0 = 0.f, a1 = 0.f, a2 = 0.f, a3 = 0.f;
  #pragma unroll 8
  for (int kk = 0; kk < 64; ++kk) {
    int k = k0 + kk;
    float w = fw1[k * 256 + n];
    a0 = fmaf(h_obs[(r0 + 0) * 256 + k], w, a0);
    a1 = fmaf(h_obs[(r0 + 1) * 256 + k], w, a1);
    a2 = fmaf(h_obs[(r0 + 2) * 256 + k], w, a2);
    a3 = fmaf(h_obs[(r0 + 3) * 256 + k], w, a3);
  }
  s_red[ks][0][n] = a0; s_red[ks][1][n] = a1;
  s_red[ks][2][n] = a2; s_red[ks][3][n] = a3;
  __syncthreads();
  if (ks == 0) {
    float bb = fb1[n];
    #pragma unroll
    for (int r = 0; r < 4; ++r) {
      float v = s_red[0][r][n] + s_red[1][r][n] + s_red[2][r][n] + s_red[3][r][n] + bb;
      s_hid[r][n] = fmaxf(v, 0.f);
    }
  }
  __syncthreads();
  float c0 = 0.f, c1 = 0.f, c2 = 0.f, c3 = 0.f;
  #pragma unroll 8
  for (int kk = 0; kk < 64; ++kk) {
    int k = k0 + kk;
    float w = fw2[k * 256 + n];
    c0 = fmaf(s_hid[0][k], w, c0);
    c1 = fmaf(s_hid[1][k], w, c1);
    c2 = fmaf(s_hid[2][k], w, c2);
    c3 = fmaf(s_hid[3][k], w, c3);
  }
  __syncthreads();
  s_red[ks][0][n] = c0; s_red[ks][1][n] = c1;
  s_red[ks][2][n] = c2; s_red[ks][3][n] = c3;
  __syncthreads();
  if (ks == 0) {
    float bb = fb2[n];
    float vr[4];
    #pragma unroll
    for (int r = 0; r < 4; ++r)
      vr[r] = s_red[0][r][n] + s_red[1][r][n] + s_red[2][r][n] + s_red[3][r][n] + bb;
    // transpose store: thread n owns column (h,d); 4 consecutive o
    const int h  = n >> 5, d = n & 31;
    const int bb_ = r0 >> 9, o0 = r0 & 511;
    half4 pv;
    #pragma unroll
    for (int r = 0; r < 4; ++r) pv[r] = (_Float16)vr[r];
    *(half4*)(VT + ((size_t)((bb_ * 8 + h) * 32 + d)) * 512 + o0) = pv;
  }
}

// ---------------------------------------------------------------------------
// Fused attention + out_proj. QT=2 per block, 512 threads (8 waves).
// Phase 1: f16 MFMA delta; ao built in-register (rank-3 pos projection).
// Phase 2+3: per-wave (=head), barrier-free (r4 structure). Changes vs r4:
//   - no-max softmax (p = exp(l - ln16), scale cancels; sum butterfly
//     deferred past PV -> no pre-PV cross-lane chain)
//   - softmax thread owns 8 consecutive o -> b128 logits reads / P stores
//   - VT staging slices XOR-swizzled (pre-swizzled gll SOURCE lane + swizzled
//     read slot) -> am reads 4-way -> 2-way bank aliasing (free)
__global__ __launch_bounds__(512, 4) void attn_fused(
    const _Float16* __restrict__ VT,     // [b][h][d][o] f16
    const float* __restrict__ kw1,       // (9, 256)
    const float* __restrict__ kb1,       // (256)
    const float* __restrict__ kw2,       // (256, 8)
    const float* __restrict__ kb2,       // (8)
    const float* __restrict__ log_sigma, // (8)
    const float* __restrict__ pos_obs,   // (B*NO, 3)
    const float* __restrict__ pos_query, // (B*NQ, 3)
    const float* __restrict__ ow, const float* __restrict__ obias,
    const float* __restrict__ vw, const float* __restrict__ vbias,
    float* __restrict__ out)
{
  __shared__ __align__(16) float s_logits[2][8 * LPAD];   // 33024 B; ph3: per-wave VT stage
  __shared__ __align__(16) _Float16 s_P16[2][8][520];     // 16640 B (P, f16)
  __shared__ half8 s_Bh[512];                             // 8192 B (kw2 frags; ph3: slice bufs)
  __shared__ __align__(16) float s_pool[2048];            // 8192 B
  __shared__ __align__(16) float s_po[3][516];            // 6192 B (pos_obs, SoA)
  __shared__ __align__(16) _Float16 s_co[3][264];         // 1584 B (ao coeff table)

  _Float16* s_aq2 = (_Float16*)s_pool;   // [2][256] f16 (phase 1 only)
  float*    s_hv   = s_pool;             // [(q*2+kind)*256+hd] (phase 3/4)
  float*    s_pred = s_pool + 1024;      // [ks][mode][q][128]  (phase 4)

  const int t   = threadIdx.x;
  const int bq0 = blockIdx.x * 2;
  const int b   = bq0 >> 9;

  // ---- prologue -----------------------------------------------------------
  float pqx[2], pqy[2], pqz[2];
  #pragma unroll
  for (int q = 0; q < 2; ++q) {
    pqx[q] = pos_query[(bq0 + q) * 3 + 0];
    pqy[q] = pos_query[(bq0 + q) * 3 + 1];
    pqz[q] = pos_query[(bq0 + q) * 3 + 2];
  }
  // aq[q][j] in f16
  {
    const int q = t >> 8, j = t & 255;
    float c0 = kw1[0 * 256 + j] + kw1[6 * 256 + j];
    float c1 = kw1[1 * 256 + j] + kw1[7 * 256 + j];
    float c2 = kw1[2 * 256 + j] + kw1[8 * 256 + j];
    s_aq2[q * 256 + j] = (_Float16)
        fmaf(pqx[q], c0, fmaf(pqy[q], c1, fmaf(pqz[q], c2, kb1[j])));
  }
  // ao coefficient table (rank-3): co[c][j], f16
  if (t < 256) {
    const int j = t;
    s_co[0][j] = (_Float16)(kw1[3 * 256 + j] - kw1[6 * 256 + j]);
    s_co[1][j] = (_Float16)(kw1[4 * 256 + j] - kw1[7 * 256 + j]);
    s_co[2][j] = (_Float16)(kw1[5 * 256 + j] - kw1[8 * 256 + j]);
  }
  // pos_obs SoA + logits prefill (rbf + kb2) for o = t, both q, all h.
  // log(exp(x)+1e-8) ~= max(x, log(1e-8)); clamp region weight < e^-15.
  {
    const int o = t;
    const float* p = pos_obs + (size_t)(b * NO + o) * 3;
    float px = p[0], py = p[1], pz = p[2];
    s_po[0][o] = px; s_po[1][o] = py; s_po[2][o] = pz;
    float d2q[2];
    #pragma unroll
    for (int q = 0; q < 2; ++q) {
      float r0 = pqx[q] - px, r1 = pqy[q] - py, r2 = pqz[q] - pz;
      d2q[q] = r0 * r0 + r1 * r1 + r2 * r2;
    }
    #pragma unroll
    for (int h = 0; h < 8; ++h) {
      float sg  = __expf(log_sigma[h]);
      float inv = 1.0f / (sg * sg + 1e-6f);
      float kbv = kb2[h];
      s_logits[0][h * LPAD + o] = fmaxf(-d2q[0] * inv, -18.420681f) + kbv;
      s_logits[1][h * LPAD + o] = fmaxf(-d2q[1] * inv, -18.420681f) + kbv;
    }
  }
  // B fragments: kw2 as f16
  {
    const int kstep = t >> 6, lane = t & 63;
    const int nh = lane & 15;
    const int kb_ = kstep * 32 + ((lane >> 4) & 3) * 8;
    half8 b8;
    #pragma unroll
    for (int i = 0; i < 8; ++i) {
      float v = (nh < 8) ? kw2[(kb_ + i) * 8 + nh] : 0.f;
      b8[i] = (_Float16)v;
    }
    s_Bh[kstep * 64 + lane] = b8;
  }
  __syncthreads();

  // ---- phase 1: f16 MFMA delta; A = relu(aq + pos.co) all in packed f16 ---
  {
    const int wave = t >> 6, lane = t & 63;
    const int quad = lane >> 4, mrow = lane & 15;
    const int tb   = wave * 4;
    _Float16 pxh[4], pyh[4], pzh[4];
    #pragma unroll
    for (int jt = 0; jt < 4; ++jt) {
      const int o = (tb + jt) * 16 + mrow;
      pxh[jt] = (_Float16)s_po[0][o];
      pyh[jt] = (_Float16)s_po[1][o];
      pzh[jt] = (_Float16)s_po[2][o];
    }
    f32x4 C[2][4];
    #pragma unroll
    for (int q = 0; q < 2; ++q)
      #pragma unroll
      for (int jt = 0; jt < 4; ++jt) C[q][jt] = (f32x4){0.f, 0.f, 0.f, 0.f};

    const half8 z8 = {0, 0, 0, 0, 0, 0, 0, 0};
    #pragma unroll
    for (int kstep = 0; kstep < 8; ++kstep) {
      const int koff = kstep * 32 + quad * 8;
      half8 c0 = *(const half8*)&s_co[0][koff];
      half8 c1 = *(const half8*)&s_co[1][koff];
      half8 c2 = *(const half8*)&s_co[2][koff];
      half8 aq0 = *(const half8*)(s_aq2 + koff);
      half8 aq1 = *(const half8*)(s_aq2 + 256 + koff);
      half8 bh  = s_Bh[kstep * 64 + lane];
      #pragma unroll
      for (int jt = 0; jt < 4; ++jt) {
        half8 ao = fma8(splat8(pxh[jt]), c0,
                   fma8(splat8(pyh[jt]), c1, splat8(pzh[jt]) * c2));
        half8 a0 = max8(aq0 + ao, z8);
        half8 a1 = max8(aq1 + ao, z8);
        C[0][jt] = __builtin_amdgcn_mfma_f32_16x16x32_f16(a0, bh, C[0][jt], 0, 0, 0);
        C[1][jt] = __builtin_amdgcn_mfma_f32_16x16x32_f16(a1, bh, C[1][jt], 0, 0, 0);
      }
    }
    // epilogue: D[n=h=lane&15][m=quad*4+r]; add delta into prefilled logits
    const int hh = lane & 15;
    if (hh < 8) {
      #pragma unroll
      for (int q = 0; q < 2; ++q)
        #pragma unroll
        for (int jt = 0; jt < 4; ++jt) {
          const int ob2 = (tb + jt) * 16 + quad * 4;
          #pragma unroll
          for (int r = 0; r < 4; ++r)
            s_logits[q][hh * LPAD + ob2 + r] += C[q][jt][r];
        }
    }
  }
  __syncthreads();   // logits complete; waves drift from here to phase 4

  // ---- phase 2+3: per-wave (=head), barrier-free --------------------------
  {
    const int h = t >> 6, lane = t & 63;
    const int kg = lane >> 4, dl = lane & 15;
    // wave-private staging buffers (all dead for everyone else):
    //   buf0 = own s_Bh slot; buf1/buf3 = own q0 logits row; buf2 = own q1 row
    char* stg0 = (char*)s_Bh + h * 1024;
    char* b1   = (char*)&s_logits[0][h * LPAD];
    char* b3   = b1 + 1024;
    char* b2   = (char*)&s_logits[1][h * LPAD];
    // pre-swizzled SOURCE lane: LDS stays linear per gll rules; physical slot
    // P=16*lane holds logical slot 16*(lane ^ ((lane>>3)&1))
    const int lp = lane ^ ((lane >> 3) & 1);
    const _Float16* vsrc = VT + ((size_t)(b * 8 + h) << 14)
                         + (lp >> 1) * 512 + (lp & 1) * 8;
    gll16(vsrc, stg0);                 // slice 0: hides under softmax

    // no-max softmax: p = exp(l - ln16). Bounded logits (clamped prefill,
    // rbf<=0, small delta) keep p comfortably in f16-normal range; the 2^-4
    // scale cancels exactly in normalization. Sum butterfly deferred past PV.
    float s0 = 0.f, s1 = 0.f;
    {
      const float* pl0 = &s_logits[0][h * LPAD] + lane * 8;
      const float* pl1 = &s_logits[1][h * LPAD] + lane * 8;
      half8 P0, P1;
      #pragma unroll
      for (int k = 0; k < 8; ++k) {
        float p0 = __expf(pl0[k] - 2.7725887f);   // ln 16
        float p1 = __expf(pl1[k] - 2.7725887f);
        s0 += p0; s1 += p1;
        P0[k] = (_Float16)p0;
        P1[k] = (_Float16)p1;
      }
      *(half8*)&s_P16[0][h][lane * 8] = P0;
      *(half8*)&s_P16[1][h][lane * 8] = P1;
    }
    // own logits rows now fully read -> become staging buffers
    gll16(vsrc + 16, b1);              // slice 1
    gll16(vsrc + 32, b2);              // slice 2
    gll16(vsrc + 48, b3);              // slice 3

    // swizzled read: 16B-slot bit = (kg&1) ^ ((dl>>2)&1) -> 2-way banks (free)
    const int slot = ((kg & 1) ^ ((dl >> 2) & 1)) << 4;
    const char* pE = ((kg & 2) ? b1 : stg0) + dl * 32 + slot;
    const char* pO = ((kg & 2) ? b3 : b2)   + dl * 32 + slot;
    const _Float16* pB = &s_P16[lane & 1][h][0];
    f32x4 Cm0 = {0.f, 0.f, 0.f, 0.f}, Cm1 = Cm0, Cv0 = Cm0, Cv1 = Cm0;
    #pragma unroll
    for (int kp = 0; kp < 8; ++kp) {
      // even K-step: slices 4kp, 4kp+1 (buf0/buf1)
      asm volatile("s_waitcnt vmcnt(2)" ::: "memory");
      {
        half8 am0 = *(const half8*)(pE);
        half8 am1 = *(const half8*)(pE + 512);       // d + 16
        half8 pb  = *(const half8*)(pB + (2 * kp) * 32 + kg * 8);
        half8 av0 = am0 * am0;
        half8 av1 = am1 * am1;
        __builtin_amdgcn_s_setprio(1);
        Cm0 = __builtin_amdgcn_mfma_f32_16x16x32_f16(am0, pb, Cm0, 0, 0, 0);
        Cm1 = __builtin_amdgcn_mfma_f32_16x16x32_f16(am1, pb, Cm1, 0, 0, 0);
        Cv0 = __builtin_amdgcn_mfma_f32_16x16x32_f16(av0, pb, Cv0, 0, 0, 0);
        Cv1 = __builtin_amdgcn_mfma_f32_16x16x32_f16(av1, pb, Cv1, 0, 0, 0);
        __builtin_amdgcn_s_setprio(0);
      }
      if (kp < 7) {
        asm volatile("s_waitcnt lgkmcnt(0)" ::: "memory");  // reads done; safe to overwrite
        gll16(vsrc + (4 * kp + 4) * 16, stg0);
        gll16(vsrc + (4 * kp + 5) * 16, b1);
      }
      // odd K-step: slices 4kp+2, 4kp+3 (buf2/buf3)
      if (kp < 7) asm volatile("s_waitcnt vmcnt(2)" ::: "memory");
      else        asm volatile("s_waitcnt vmcnt(0)" ::: "memory");
      {
        half8 am0 = *(const half8*)(pO);
        half8 am1 = *(const half8*)(pO + 512);
        half8 pb  = *(const half8*)(pB + (2 * kp + 1) * 32 + kg * 8);
        half8 av0 = am0 * am0;
        half8 av1 = am1 * am1;
        __builtin_amdgcn_s_setprio(1);
        Cm0 = __builtin_amdgcn_mfma_f32_16x16x32_f16(am0, pb, Cm0, 0, 0, 0);
        Cm1 = __builtin_amdgcn_mfma_f32_16x16x32_f16(am1, pb, Cm1, 0, 0, 0);
        Cv0 = __builtin_amdgcn_mfma_f32_16x16x32_f16(av0, pb, Cv0, 0, 0, 0);
        Cv1 = __builtin_amdgcn_mfma_f32_16x16x32_f16(av1, pb, Cv1, 0, 0, 0);
        __builtin_amdgcn_s_setprio(0);
      }
      if (kp < 7) {
        asm volatile("s_waitcnt lgkmcnt(0)" ::: "memory");
        gll16(vsrc + (4 * kp + 6) * 16, b2);
        gll16(vsrc + (4 * kp + 7) * 16, b3);
      }
    }
    // deferred sum reduction (off the PV critical path)
    #pragma unroll
    for (int off = 32; off >= 1; off >>= 1) {
      s0 += __shfl_xor(s0, off, 64);
      s1 += __shfl_xor(s1, off, 64);
    }
    // epilogue: C row = kg*4+r (=d_local), col = nq (=q). Normalize + var.
    const int nq = lane & 15;
    if (nq < 2) {
      const float iv = 1.0f / (nq ? s1 : s0);
      const int dbase = h * 32 + kg * 4;
      f32x4 m0, v0, m1, v1;
      #pragma unroll
      for (int r = 0; r < 4; ++r) {
        float a = Cm0[r] * iv;
        m0[r] = a; v0[r] = fmaxf(Cv0[r] * iv - a * a, 0.f);
        float c = Cm1[r] * iv;
        m1[r] = c; v1[r] = fmaxf(Cv1[r] * iv - c * c, 0.f);
      }
      *(f32x4*)(s_hv + (nq * 2 + 0) * 256 + dbase)      = m0;
      *(f32x4*)(s_hv + (nq * 2 + 1) * 256 + dbase)      = v0;
      *(f32x4*)(s_hv + (nq * 2 + 0) * 256 + dbase + 16) = m1;
      *(f32x4*)(s_hv + (nq * 2 + 1) * 256 + dbase + 16) = v1;
    }
  }
  __syncthreads();

  // ---- phase 4: out_proj, k-split 2, W read once per (mode,ks) ------------
  {
    const int ks = t >> 8, mode = (t >> 7) & 1, n = t & 127;
    const float* W  = mode ? vw : ow;
    const float* X0 = s_hv + mode * 256;        // q0
    const float* X1 = s_hv + (2 + mode) * 256;  // q1
    float a0 = 0.f, a1 = 0.f;
    const int k0 = ks * 128;
    #pragma unroll 4
    for (int k = k0; k < k0 + 128; k += 4) {
      float4 x0 = *(const float4*)&X0[k];
      float4 x1 = *(const float4*)&X1[k];
      float w0 = W[(k + 0) * 128 + n];
      float w1 = W[(k + 1) * 128 + n];
      float w2 = W[(k + 2) * 128 + n];
      float w3 = W[(k + 3) * 128 + n];
      a0 = fmaf(x0.x, w0, a0); a1 = fmaf(x1.x, w0, a1);
      a0 = fmaf(x0.y, w1, a0); a1 = fmaf(x1.y, w1, a1);
      a0 = fmaf(x0.z, w2, a0); a1 = fmaf(x1.z, w2, a1);
      a0 = fmaf(x0.w, w3, a0); a1 = fmaf(x1.w, w3, a1);
    }
    s_pred[((ks * 2 + mode) * 2 + 0) * 128 + n] = a0;   // disjoint from s_hv
    s_pred[((ks * 2 + mode) * 2 + 1) * 128 + n] = a1;
  }
  __syncthreads();
  {
    const int q = t >> 8, mode = (t >> 7) & 1, n = t & 127;
    float v = s_pred[((0 * 2 + mode) * 2 + q) * 128 + n]
            + s_pred[((1 * 2 + mode) * 2 + q) * 128 + n]
            + (mode ? vbias[n] : obias[n]);
    if (mode) v = softplus_f(v);
    out[(size_t)mode * (NB * NQ * OUT_DIM) + (size_t)(bq0 + q) * OUT_DIM + n] = v;
  }
}

// ---------------------------------------------------------------------------
extern "C" void kernel_launch(void* const* d_in, const int* in_sizes, int n_in,
                              void* d_out, int out_size, void* d_ws, size_t ws_size,
                              hipStream_t stream)
{
  const float* h_obs     = (const float*)d_in[0];
  const float* pos_obs   = (const float*)d_in[1];
  const float* pos_query = (const float*)d_in[2];
  const float* fw1       = (const float*)d_in[3];
  const float* fb1       = (const float*)d_in[4];
  const float* fw2       = (const float*)d_in[5];
  const float* fb2       = (const float*)d_in[6];
  const float* log_sigma = (const float*)d_in[7];
  const float* kw1       = (const float*)d_in[8];
  const float* kb1       = (const float*)d_in[9];
  const float* kw2       = (const float*)d_in[10];
  const float* kb2       = (const float*)d_in[11];
  const float* ow        = (const float*)d_in[12];
  const float* ob        = (const float*)d_in[13];
  const float* vw        = (const float*)d_in[14];
  const float* vb        = (const float*)d_in[15];

  float* out = (float*)d_out;
  _Float16* VT = (_Float16*)d_ws;   // 262144 f16 = 512 KB

  prep_kernel<<<256, 1024, 0, stream>>>(h_obs, fw1, fb1, fw2, fb2, VT);
  attn_fused<<<NB * NQ / 2, 512, 0, stream>>>(VT, kw1, kb1, kw2, kb2,
                                              log_sigma, pos_obs, pos_query,
                                              ow, ob, vw, vb, out);
}